// Round 2
// baseline (1372.409 us; speedup 1.0000x reference)
//
#include <hip/hip_runtime.h>
#include <hip/hip_bf16.h>

// Problem: B=128, T=2048, H=512
//   Wsum = Wa_w + Ua_w; bsum = Wa_b + Ua_b
//   pre[b,t,o]  = sum_h x[b,t,h] * Wsum[o,h] + bsum[o]
//   score[b,t]  = sum_o tanh(pre) * Va[o]        (+Va_b: softmax-invariant, dropped)
//   w = softmax_t(score);  context[b,h] = sum_t w[b,t] x[b,t,h]
// Outputs concat: context [B,H]=65536 floats, then weights [B,T]=262144 floats.
//
// R2: GEMM with NO LDS — MFMA fragments loaded directly from global (L1/L2
// served), removing the barrier-drain + staging-VALU bottleneck seen in R1
// (MfmaUtil 12%, VALUBusy 25%, all pipes idle). Grid n-tile-fastest for A-strip
// L2 reuse. Context pass rebuilt at float4/lane.

#define BB 128
#define TT 2048
#define HH 512

typedef __bf16 bf16_t;
typedef __bf16 bf16x8_t __attribute__((ext_vector_type(8)));
typedef float f32x4_t __attribute__((ext_vector_type(4)));
typedef float f32x8_t __attribute__((ext_vector_type(8)));

__device__ __forceinline__ float tanh_fast(float x) {
    // tanh(x) = 1 - 2/(e^{2x}+1); exp overflow -> +1, underflow -> -1 (correct limits)
    float e = __expf(2.0f * x);
    return 1.0f - 2.0f * __builtin_amdgcn_rcpf(e + 1.0f);
}

// ---- kernel 0: Wsum (bf16) + bsum (fp32) prep -------------------------------
__global__ void prep_kernel(const float* __restrict__ wa, const float* __restrict__ ua,
                            const float* __restrict__ wab, const float* __restrict__ uab,
                            bf16_t* __restrict__ wsum, float* __restrict__ bsum) {
    int i = blockIdx.x * 256 + threadIdx.x;   // grid 1024*256 = 262144 = H*H
    wsum[i] = (bf16_t)(wa[i] + ua[i]);
    if (i < HH) bsum[i] = wab[i] + uab[i];
}

// ---- kernel 1: fused GEMM + tanh + Va-dot -> score (atomic partials) --------
// C[m,o] = sum_k x[m,k] * Wsum[o,k]; tile 128(M) x 128(N), 4 waves 2x2, each
// wave 64x64 via 4x4 frags of mfma_f32_16x16x32_bf16. LDS-free: fragments are
// 8 consecutive k-elements per lane -> direct global loads (A: f32x8 + cvt,
// B: bf16x8). A k-slice (16 KiB) is L1-resident across the 2-wave x 4-block
// reuse; B (512 KiB total) is L2-resident.
__global__ __launch_bounds__(256) void gemm_score_kernel(
    const float* __restrict__ x, const bf16_t* __restrict__ wsum,
    const float* __restrict__ bsum, const float* __restrict__ va,
    float* __restrict__ score) {
    const int tid  = threadIdx.x;
    const int lane = tid & 63;
    const int wave = tid >> 6;
    const int wm   = (wave >> 1) * 64;
    const int wn   = (wave & 1) * 64;
    const int quad = lane >> 4;
    const int lo   = lane & 15;
    const int n0   = blockIdx.x * 128;   // n-tile fastest: 4 blocks sharing an
    const int m0   = blockIdx.y * 128;   // A strip are adjacent in dispatch

    f32x4_t acc[4][4];
#pragma unroll
    for (int mi = 0; mi < 4; ++mi)
#pragma unroll
        for (int ni = 0; ni < 4; ++ni)
            acc[mi][ni] = (f32x4_t){0.f, 0.f, 0.f, 0.f};

    // per-lane fragment base pointers (row + quad's 8-element k-run)
    const float*  xp[4];
    const bf16_t* wp[4];
#pragma unroll
    for (int mi = 0; mi < 4; ++mi)
        xp[mi] = x + (size_t)(m0 + wm + mi * 16 + lo) * HH + quad * 8;
#pragma unroll
    for (int ni = 0; ni < 4; ++ni)
        wp[ni] = wsum + (size_t)(n0 + wn + ni * 16 + lo) * HH + quad * 8;

#pragma unroll 2
    for (int k = 0; k < HH; k += 32) {
        bf16x8_t a[4], b[4];
#pragma unroll
        for (int mi = 0; mi < 4; ++mi) {
            f32x8_t u = *(const f32x8_t*)(xp[mi] + k);   // 2x dwordx4, 32B-aligned
            a[mi] = __builtin_convertvector(u, bf16x8_t);
        }
#pragma unroll
        for (int ni = 0; ni < 4; ++ni)
            b[ni] = *(const bf16x8_t*)(wp[ni] + k);      // 1x dwordx4
#pragma unroll
        for (int mi = 0; mi < 4; ++mi)
#pragma unroll
            for (int ni = 0; ni < 4; ++ni)
                acc[mi][ni] = __builtin_amdgcn_mfma_f32_16x16x32_bf16(
                    a[mi], b[ni], acc[mi][ni], 0, 0, 0);
    }

    // epilogue: score partial = sum over this tile's o-range of tanh(pre+bsum)*va
    // C/D layout: col(o) = lane&15 (+16*ni), row(m) = quad*4 + reg (+16*mi)
    float bsr[4], var[4];
#pragma unroll
    for (int ni = 0; ni < 4; ++ni) {
        int o = n0 + wn + ni * 16 + lo;
        bsr[ni] = bsum[o];
        var[ni] = va[o];
    }
#pragma unroll
    for (int mi = 0; mi < 4; ++mi) {
#pragma unroll
        for (int r = 0; r < 4; ++r) {
            float s = 0.f;
#pragma unroll
            for (int ni = 0; ni < 4; ++ni)
                s += var[ni] * tanh_fast(acc[mi][ni][r] + bsr[ni]);
            // reduce across the 16 lanes (lo) sharing this row
            s += __shfl_xor(s, 1);
            s += __shfl_xor(s, 2);
            s += __shfl_xor(s, 4);
            s += __shfl_xor(s, 8);
            if (lo == 0)
                atomicAdd(&score[m0 + wm + mi * 16 + quad * 4 + r], s);
        }
    }
}

// ---- kernel 2: softmax over T per batch -------------------------------------
__global__ void softmax_kernel(const float* __restrict__ score, float* __restrict__ wout) {
    const int b = blockIdx.x;
    const int tid = threadIdx.x;
    const int lane = tid & 63;
    const int wave = tid >> 6;
    float s[8];
    float mx = -3.4e38f;
#pragma unroll
    for (int i = 0; i < 8; ++i) {
        s[i] = score[b * TT + i * 256 + tid];
        mx = fmaxf(mx, s[i]);
    }
#pragma unroll
    for (int off = 32; off; off >>= 1) mx = fmaxf(mx, __shfl_xor(mx, off));
    __shared__ float rmx[4], rsum[4];
    if (lane == 0) rmx[wave] = mx;
    __syncthreads();
    mx = fmaxf(fmaxf(rmx[0], rmx[1]), fmaxf(rmx[2], rmx[3]));
    float e[8];
    float sum = 0.f;
#pragma unroll
    for (int i = 0; i < 8; ++i) {
        e[i] = __expf(s[i] - mx);
        sum += e[i];
    }
#pragma unroll
    for (int off = 32; off; off >>= 1) sum += __shfl_xor(sum, off);
    if (lane == 0) rsum[wave] = sum;
    __syncthreads();
    sum = rsum[0] + rsum[1] + rsum[2] + rsum[3];
    float inv = 1.0f / sum;
#pragma unroll
    for (int i = 0; i < 8; ++i)
        wout[b * TT + i * 256 + tid] = e[i] * inv;
}

// ---- kernel 3: context partials over t-chunks -------------------------------
// grid (BB, 16); block 128; thread owns 4 h columns (float4 = 16B/lane),
// 128 t per chunk. A wave covers 64*16B = a full 2KiB row-quarter... 128
// threads * 4 floats = full H row per iteration step.
__global__ void context_partial_kernel(const float* __restrict__ x,
                                       const float* __restrict__ w,
                                       float* __restrict__ part) {
    const int b = blockIdx.x, tc = blockIdx.y, tid = threadIdx.x;
    __shared__ float lw[128];
    if (tid < 128) lw[tid] = w[b * TT + tc * 128 + tid];
    __syncthreads();
    const float* xp = x + ((size_t)b * TT + tc * 128) * HH + tid * 4;
    float a0 = 0.f, a1 = 0.f, a2 = 0.f, a3 = 0.f;
#pragma unroll 4
    for (int i = 0; i < 128; ++i) {
        f32x4_t v = *(const f32x4_t*)(xp + (size_t)i * HH);
        float wv = lw[i];
        a0 = fmaf(wv, v[0], a0);
        a1 = fmaf(wv, v[1], a1);
        a2 = fmaf(wv, v[2], a2);
        a3 = fmaf(wv, v[3], a3);
    }
    f32x4_t o = {a0, a1, a2, a3};
    *(f32x4_t*)&part[((size_t)tc * BB + b) * HH + tid * 4] = o;
}

// ---- kernel 4: reduce partials -> context -----------------------------------
__global__ void context_reduce_kernel(const float* __restrict__ part, float* __restrict__ out) {
    int idx = blockIdx.x * 256 + threadIdx.x;   // < BB*HH = 65536
    float s = 0.f;
#pragma unroll
    for (int tc = 0; tc < 16; ++tc) s += part[tc * (BB * HH) + idx];
    out[idx] = s;
}

extern "C" void kernel_launch(void* const* d_in, const int* in_sizes, int n_in,
                              void* d_out, int out_size, void* d_ws, size_t ws_size,
                              hipStream_t stream) {
    const float* x   = (const float*)d_in[0];   // [B,T,H]
    const float* wa  = (const float*)d_in[1];   // [H,H]
    const float* wab = (const float*)d_in[2];   // [H]
    const float* ua  = (const float*)d_in[3];   // [H,H]
    const float* uab = (const float*)d_in[4];   // [H]
    const float* vaw = (const float*)d_in[5];   // [1,H]
    // d_in[6] = Va_b: softmax shift-invariant, unused

    float* ctx_out = (float*)d_out;             // [B,H]
    float* w_out   = (float*)d_out + BB * HH;   // [B,T]

    char* ws = (char*)d_ws;
    float*  score = (float*)ws;                                   // 1 MiB
    bf16_t* wsum  = (bf16_t*)(ws + (1 << 20));                    // 512 KiB
    float*  bsum  = (float*)(ws + (1 << 20) + HH * HH * 2);       // 2 KiB
    float*  part  = (float*)(ws + (1 << 20) + HH * HH * 2 + 4096);// 4 MiB

    hipMemsetAsync(score, 0, (size_t)BB * TT * sizeof(float), stream);
    prep_kernel<<<HH * HH / 256, 256, 0, stream>>>(wa, ua, wab, uab, wsum, bsum);
    gemm_score_kernel<<<dim3(HH / 128, BB * TT / 128), 256, 0, stream>>>(
        x, wsum, bsum, vaw, score);
    softmax_kernel<<<BB, 256, 0, stream>>>(score, w_out);
    context_partial_kernel<<<dim3(BB, 16), 128, 0, stream>>>(x, w_out, part);
    context_reduce_kernel<<<BB * HH / 256, 256, 0, stream>>>(part, ctx_out);
}

// Round 3
// 954.412 us; speedup vs baseline: 1.4380x; 1.4380x over previous
//
#include <hip/hip_runtime.h>
#include <hip/hip_bf16.h>

// Problem: B=128, T=2048, H=512
//   Wsum = Wa_w + Ua_w; bsum = Wa_b + Ua_b
//   pre[b,t,o]  = sum_h x[b,t,h] * Wsum[o,h] + bsum[o]
//   score[b,t]  = sum_o tanh(pre) * Va[o]        (+Va_b: softmax-invariant, dropped)
//   w = softmax_t(score);  context[b,h] = sum_t w[b,t] x[b,t,h]
// Outputs concat: context [B,H]=65536 floats, then weights [B,T]=262144 floats.
//
// R3: m97-structure GEMM. x pre-converted to bf16 once (R1 converted it 4x
// in-kernel = half its VALUBusy); A and B both staged via global_load_lds
// width=16 (no VGPR roundtrip); 16B pad between 8-row LDS chunks (legal with
// global_load_lds since one wave-copy = exactly one 1024B chunk) to cut
// fragment ds_read_b128 conflicts 16-way -> ~8-way. Epilogue writes unique
// spart[8][M] slices -> no atomics, no memset. Context reads bf16 (half bytes).
// R2's LDS-free scattered-fragment loads were TA-throughput-bound (MfmaUtil
// 7%): reverted.

#define BB 128
#define TT 2048
#define HH 512
#define MM (BB * TT)  // 262144 rows

typedef __bf16 bf16_t;
typedef __bf16 bf16x8_t __attribute__((ext_vector_type(8)));
typedef float f32x4_t __attribute__((ext_vector_type(4)));
typedef float f32x8_t __attribute__((ext_vector_type(8)));

// LDS tile: 16 chunks of (8 rows x 128 B) + 16 B pad = 1040 B/chunk
#define CHUNK 1040
#define TILE_LDS (16 * CHUNK)

__device__ __forceinline__ float tanh_fast(float x) {
    // tanh(x) = 1 - 2/(e^{2x}+1); exp overflow -> +1, underflow -> -1
    float e = __expf(2.0f * x);
    return 1.0f - 2.0f * __builtin_amdgcn_rcpf(e + 1.0f);
}

__device__ __forceinline__ void async_copy16(void* lds, const void* g) {
    // wave-uniform LDS base; HW writes lane i at base + i*16
    __builtin_amdgcn_global_load_lds(
        (const __attribute__((address_space(1))) unsigned int*)g,
        (__attribute__((address_space(3))) unsigned int*)lds, 16, 0, 0);
}

// ---- kernel 0: x fp32 -> bf16 ------------------------------------------------
__global__ void convert_kernel(const float* __restrict__ x, bf16_t* __restrict__ xb) {
    size_t i = ((size_t)blockIdx.x * 256 + threadIdx.x) * 8;
    f32x8_t v = *(const f32x8_t*)(x + i);
    *(bf16x8_t*)(xb + i) = __builtin_convertvector(v, bf16x8_t);
}

// ---- kernel 1: Wsum (bf16) + bsum (fp32) prep -------------------------------
__global__ void prep_kernel(const float* __restrict__ wa, const float* __restrict__ ua,
                            const float* __restrict__ wab, const float* __restrict__ uab,
                            bf16_t* __restrict__ wsum, float* __restrict__ bsum) {
    int i = blockIdx.x * 256 + threadIdx.x;  // 1024*256 = H*H
    wsum[i] = (bf16_t)(wa[i] + ua[i]);
    if (i < HH) bsum[i] = wab[i] + uab[i];
}

// ---- kernel 2: fused GEMM + tanh + Va-dot -> spart --------------------------
// tile 128(M) x 128(N), BK=64, waves 2x2, wave 64x64 via 4x4 16x16x32 frags.
// ABF16: A from pre-converted xb via global_load_lds; else fp32 x + in-reg cvt.
template <bool ABF16>
__global__ __launch_bounds__(256, 4) void gemm_score_kernel(
    const float* __restrict__ xf, const bf16_t* __restrict__ xb,
    const bf16_t* __restrict__ wsum, const float* __restrict__ bsum,
    const float* __restrict__ va, float* __restrict__ spart) {
    __shared__ __align__(16) char As[TILE_LDS];
    __shared__ __align__(16) char Bs[TILE_LDS];

    const int tid  = threadIdx.x;
    const int lane = tid & 63;
    const int wave = tid >> 6;
    const int wm   = (wave >> 1) * 64;
    const int wn   = (wave & 1) * 64;
    const int quad = lane >> 4;
    const int lo   = lane & 15;
    const int n0   = blockIdx.x * 128;  // n fastest: 4 blocks share the A strip
    const int m0   = blockIdx.y * 128;

    f32x4_t acc[4][4];
#pragma unroll
    for (int mi = 0; mi < 4; ++mi)
#pragma unroll
        for (int ni = 0; ni < 4; ++ni)
            acc[mi][ni] = (f32x4_t){0.f, 0.f, 0.f, 0.f};

    // staging pointers: wave w owns chunks w*4..w*4+3 (8 rows each)
    const int ch = wave * 4;
    const bf16_t* gB = wsum + (size_t)(n0 + ch * 8 + (lane >> 3)) * HH + (lane & 7) * 8;
    char* lB = Bs + ch * CHUNK;
    const bf16_t* gA = nullptr;
    const float*  gAf = nullptr;
    char* lA = As + ch * CHUNK;
    if constexpr (ABF16)
        gA = xb + (size_t)(m0 + ch * 8 + (lane >> 3)) * HH + (lane & 7) * 8;
    else
        gAf = xf + (size_t)(m0 + (tid >> 3)) * HH + (tid & 7) * 8;

    // fragment read pointers (chunk-padded layout)
    const char* pa[4];
    const char* pb[4];
#pragma unroll
    for (int mi = 0; mi < 4; ++mi) {
        int r = wm + mi * 16 + lo;
        pa[mi] = As + (r >> 3) * CHUNK + (r & 7) * 128 + quad * 16;
    }
#pragma unroll
    for (int ni = 0; ni < 4; ++ni) {
        int r = wn + ni * 16 + lo;
        pb[ni] = Bs + (r >> 3) * CHUNK + (r & 7) * 128 + quad * 16;
    }

    for (int k0 = 0; k0 < HH; k0 += 64) {
#pragma unroll
        for (int c = 0; c < 4; ++c)
            async_copy16(lB + c * CHUNK, gB + (size_t)c * 8 * HH + k0);
        if constexpr (ABF16) {
#pragma unroll
            for (int c = 0; c < 4; ++c)
                async_copy16(lA + c * CHUNK, gA + (size_t)c * 8 * HH + k0);
        } else {
#pragma unroll
            for (int p = 0; p < 4; ++p) {
                int row = (tid >> 3) + p * 32;
                f32x8_t u = *(const f32x8_t*)(gAf + (size_t)p * 32 * HH + k0);
                *(bf16x8_t*)(As + (row >> 3) * CHUNK + (row & 7) * 128 + (tid & 7) * 16) =
                    __builtin_convertvector(u, bf16x8_t);
            }
        }
        __syncthreads();
#pragma unroll
        for (int kk = 0; kk < 2; ++kk) {
            bf16x8_t a[4], b[4];
#pragma unroll
            for (int mi = 0; mi < 4; ++mi)
                a[mi] = *(const bf16x8_t*)(pa[mi] + kk * 64);
#pragma unroll
            for (int ni = 0; ni < 4; ++ni)
                b[ni] = *(const bf16x8_t*)(pb[ni] + kk * 64);
#pragma unroll
            for (int mi = 0; mi < 4; ++mi)
#pragma unroll
                for (int ni = 0; ni < 4; ++ni)
                    acc[mi][ni] = __builtin_amdgcn_mfma_f32_16x16x32_bf16(
                        a[mi], b[ni], acc[mi][ni], 0, 0, 0);
        }
        __syncthreads();
    }

    // epilogue: C/D layout col(o) = lane&15 (+16*ni), row(m) = quad*4+reg (+16*mi)
    float bsr[4], var[4];
#pragma unroll
    for (int ni = 0; ni < 4; ++ni) {
        int o = n0 + wn + ni * 16 + lo;
        bsr[ni] = bsum[o];
        var[ni] = va[o];
    }
    const int ob = (n0 + wn) >> 6;  // 0..7, unique o-block per wave-column
#pragma unroll
    for (int mi = 0; mi < 4; ++mi) {
#pragma unroll
        for (int r = 0; r < 4; ++r) {
            float s = 0.f;
#pragma unroll
            for (int ni = 0; ni < 4; ++ni)
                s += var[ni] * tanh_fast(acc[mi][ni][r] + bsr[ni]);
            s += __shfl_xor(s, 1);
            s += __shfl_xor(s, 2);
            s += __shfl_xor(s, 4);
            s += __shfl_xor(s, 8);
            if (lo == 0)
                spart[(size_t)ob * MM + m0 + wm + mi * 16 + quad * 4 + r] = s;
        }
    }
}

// ---- kernel 3: sum 8 spart slices + softmax over T --------------------------
__global__ void softmax_kernel(const float* __restrict__ spart, float* __restrict__ wout) {
    const int b = blockIdx.x;
    const int tid = threadIdx.x;
    const int lane = tid & 63;
    const int wave = tid >> 6;
    float s[8];
    float mx = -3.4e38f;
#pragma unroll
    for (int i = 0; i < 8; ++i) {
        int m = b * TT + i * 256 + tid;
        float v = 0.f;
#pragma unroll
        for (int ob = 0; ob < 8; ++ob) v += spart[(size_t)ob * MM + m];
        s[i] = v;
        mx = fmaxf(mx, v);
    }
#pragma unroll
    for (int off = 32; off; off >>= 1) mx = fmaxf(mx, __shfl_xor(mx, off));
    __shared__ float rmx[4], rsum[4];
    if (lane == 0) rmx[wave] = mx;
    __syncthreads();
    mx = fmaxf(fmaxf(rmx[0], rmx[1]), fmaxf(rmx[2], rmx[3]));
    float e[8];
    float sum = 0.f;
#pragma unroll
    for (int i = 0; i < 8; ++i) {
        e[i] = __expf(s[i] - mx);
        sum += e[i];
    }
#pragma unroll
    for (int off = 32; off; off >>= 1) sum += __shfl_xor(sum, off);
    if (lane == 0) rsum[wave] = sum;
    __syncthreads();
    sum = rsum[0] + rsum[1] + rsum[2] + rsum[3];
    float inv = 1.0f / sum;
#pragma unroll
    for (int i = 0; i < 8; ++i)
        wout[b * TT + i * 256 + tid] = e[i] * inv;
}

// ---- kernel 4a: context partials from bf16 xb (16 B/lane, wave-per-row) -----
__global__ void context_partial_bf16(const bf16_t* __restrict__ xb,
                                     const float* __restrict__ w,
                                     float* __restrict__ part) {
    const int b = blockIdx.x, tc = blockIdx.y, tid = threadIdx.x;
    const int wave = tid >> 6, lane = tid & 63;
    __shared__ float lw[128];
    __shared__ float red[4][HH];
    if (tid < 128) lw[tid] = w[b * TT + tc * 128 + tid];
    __syncthreads();
    const bf16_t* xp = xb + (size_t)(b * TT + tc * 128 + wave) * HH + lane * 8;
    f32x8_t acc = {0.f, 0.f, 0.f, 0.f, 0.f, 0.f, 0.f, 0.f};
#pragma unroll 4
    for (int i = 0; i < 32; ++i) {
        bf16x8_t v = *(const bf16x8_t*)(xp + (size_t)i * 4 * HH);
        f32x8_t vf = __builtin_convertvector(v, f32x8_t);
        float wv = lw[wave + i * 4];
#pragma unroll
        for (int j = 0; j < 8; ++j) acc[j] = fmaf(wv, vf[j], acc[j]);
    }
#pragma unroll
    for (int j = 0; j < 8; ++j) red[wave][lane * 8 + j] = acc[j];
    __syncthreads();
    float s0 = red[0][tid] + red[1][tid] + red[2][tid] + red[3][tid];
    float s1 = red[0][tid + 256] + red[1][tid + 256] + red[2][tid + 256] + red[3][tid + 256];
    float* po = part + ((size_t)tc * BB + b) * HH;
    po[tid] = s0;
    po[tid + 256] = s1;
}

// ---- kernel 4b: context partials from fp32 x (fallback) ---------------------
__global__ void context_partial_f32(const float* __restrict__ x,
                                    const float* __restrict__ w,
                                    float* __restrict__ part) {
    const int b = blockIdx.x, tc = blockIdx.y, tid = threadIdx.x;
    __shared__ float lw[128];
    if (tid < 128) lw[tid] = w[b * TT + tc * 128 + tid];
    __syncthreads();
    const float* xp = x + ((size_t)b * TT + tc * 128) * HH + tid * 4;
    f32x4_t a = {0.f, 0.f, 0.f, 0.f};
#pragma unroll 4
    for (int i = 0; i < 128; ++i) {
        f32x4_t v = *(const f32x4_t*)(xp + (size_t)i * HH);
        float wv = lw[i];
#pragma unroll
        for (int j = 0; j < 4; ++j) a[j] = fmaf(wv, v[j], a[j]);
    }
    *(f32x4_t*)&part[((size_t)tc * BB + b) * HH + tid * 4] = a;
}

// ---- kernel 5: reduce partials -> context -----------------------------------
__global__ void context_reduce_kernel(const float* __restrict__ part, float* __restrict__ out) {
    int idx = blockIdx.x * 256 + threadIdx.x;  // < BB*HH
    float s = 0.f;
#pragma unroll
    for (int tc = 0; tc < 16; ++tc) s += part[(size_t)tc * (BB * HH) + idx];
    out[idx] = s;
}

extern "C" void kernel_launch(void* const* d_in, const int* in_sizes, int n_in,
                              void* d_out, int out_size, void* d_ws, size_t ws_size,
                              hipStream_t stream) {
    const float* x   = (const float*)d_in[0];
    const float* wa  = (const float*)d_in[1];
    const float* wab = (const float*)d_in[2];
    const float* ua  = (const float*)d_in[3];
    const float* uab = (const float*)d_in[4];
    const float* vaw = (const float*)d_in[5];
    // d_in[6] = Va_b: softmax shift-invariant, unused

    float* ctx_out = (float*)d_out;
    float* w_out   = (float*)d_out + BB * HH;

    const size_t XB_B    = (size_t)MM * HH * 2;        // 256 MiB
    const size_t WSUM_B  = (size_t)HH * HH * 2;        // 512 KiB
    const size_t BSUM_B  = 4096;
    const size_t SPART_B = (size_t)8 * MM * 4;         // 8 MiB
    const size_t PART_B  = (size_t)16 * BB * HH * 4;   // 4 MiB
    const size_t NEED_FAST = XB_B + WSUM_B + BSUM_B + SPART_B + PART_B;

    char* ws = (char*)d_ws;
    const bool fast = (ws_size >= NEED_FAST);

    bf16_t* xb    = (bf16_t*)ws;                        // fast path only
    char*   base  = fast ? ws + XB_B : ws;
    bf16_t* wsum  = (bf16_t*)base;
    float*  bsum  = (float*)(base + WSUM_B);
    float*  spart = (float*)(base + WSUM_B + BSUM_B);
    float*  part  = (float*)(base + WSUM_B + BSUM_B + SPART_B);

    prep_kernel<<<HH * HH / 256, 256, 0, stream>>>(wa, ua, wab, uab, wsum, bsum);
    if (fast) {
        convert_kernel<<<(int)((size_t)MM * HH / 8 / 256), 256, 0, stream>>>(x, xb);
        gemm_score_kernel<true><<<dim3(4, MM / 128), 256, 0, stream>>>(
            x, xb, wsum, bsum, vaw, spart);
    } else {
        gemm_score_kernel<false><<<dim3(4, MM / 128), 256, 0, stream>>>(
            x, nullptr, wsum, bsum, vaw, spart);
    }
    softmax_kernel<<<BB, 256, 0, stream>>>(spart, w_out);
    if (fast)
        context_partial_bf16<<<dim3(BB, 16), 256, 0, stream>>>(xb, w_out, part);
    else
        context_partial_f32<<<dim3(BB, 16), 128, 0, stream>>>(x, w_out, part);
    context_reduce_kernel<<<BB * HH / 256, 256, 0, stream>>>(part, ctx_out);
}